// Round 19
// baseline (155.918 us; speedup 1.0000x reference)
//
#include <hip/hip_runtime.h>
#include <hip/hip_bf16.h>

// LinearShift forward:
//   out = q16(input) @ (exp2(round(shift))*sign(sign)).T + q16(bias)
// R19 = R17 VERBATIM (session-best verified config; R18's 1-barrier variant
// raced via inter-wave skew -- 2 barriers/K-tile is the structural minimum
// for this staging topology).
// GEMM: 256x256 tile, BK=64, 16x16x32 MFMA, 8 waves (2Mx4N), 128KiB LDS
// double-buffered half-tiles, global_load_lds w=16 + inverse-swizzled source,
// 3-bit XOR read swizzle (0 conflicts), 2 barriers/K-tile (end-ph1 WAR fence
// + end-ph3 boundary), single counted vmcnt(4)/tile, no lgkm pins, NO setprio
// (R17: removing it was +5.6%), bijective XCD blockIdx swizzle.
// Measured: GEMM 107.4us (1283 TF, 51.5% dense), MfmaUtil 57.3, total 155.3us.

#define BM 256
#define BN 256
#define BK 64

typedef __bf16 bf16_t;
typedef __attribute__((ext_vector_type(8))) __bf16 bf16x8;
typedef __attribute__((ext_vector_type(4))) __bf16 bf16x4;
typedef __attribute__((ext_vector_type(4))) float f32x4;

__device__ __forceinline__ float q16(float x) {
    // floor-quantize to 2^-16 steps, clamp to [-2^15, 2^15 - 1]
    float f = floorf(x * 65536.0f) * (1.0f / 65536.0f);
    return fminf(fmaxf(f, -32768.0f), 32767.0f);
}

// fused: element i of input -> Aq; element i of (shift,sign) -> Wq (nA == nW)
__global__ void convert_kernel(const float* __restrict__ in,
                               const float* __restrict__ shift,
                               const float* __restrict__ sign_,
                               bf16_t* __restrict__ aq,
                               bf16_t* __restrict__ wq, int nvec) {
    int stride = gridDim.x * blockDim.x;
    for (int i = blockIdx.x * blockDim.x + threadIdx.x; i < nvec; i += stride) {
        float4 v = reinterpret_cast<const float4*>(in)[i];
        bf16x4 oa;
        oa[0] = (bf16_t)q16(v.x);
        oa[1] = (bf16_t)q16(v.y);
        oa[2] = (bf16_t)q16(v.z);
        oa[3] = (bf16_t)q16(v.w);
        reinterpret_cast<bf16x4*>(aq)[i] = oa;

        float4 sh = reinterpret_cast<const float4*>(shift)[i];
        float4 sg = reinterpret_cast<const float4*>(sign_)[i];
        float shs[4] = {sh.x, sh.y, sh.z, sh.w};
        float sgs[4] = {sg.x, sg.y, sg.z, sg.w};
        bf16x4 ow;
#pragma unroll
        for (int j = 0; j < 4; ++j) {
            float s = fminf(fmaxf(sgs[j], -1.0f), 1.0f);
            float sv = (s > 0.0f) ? 1.0f : ((s < 0.0f) ? -1.0f : 0.0f);
            ow[j] = (bf16_t)(exp2f(rintf(shs[j])) * sv);
        }
        reinterpret_cast<bf16x4*>(wq)[i] = ow;
    }
}

// ---- 256x256 8-phase bf16 GEMM: C[M][N] = A[M][K]*B[N][K]^T + q16(bias)[N]

#define VMW(N) asm volatile("s_waitcnt vmcnt(" #N ")" ::: "memory")
// raw barrier + zero-cost compiler memory fence
#define BARF() do { __builtin_amdgcn_s_barrier(); asm volatile("" ::: "memory"); } while (0)

// stage one half-tile (128 rows x 64 cols, 2 x global_load_lds w=16 per thread)
#define STAGE(LDSOFF, SRC) do {                                                          \
    const bf16_t* _s = (SRC);                                                            \
    bf16_t* _d = &lds[(LDSOFF)] + tid * 8;                                               \
    __builtin_amdgcn_global_load_lds((const __attribute__((address_space(1))) void*)_s,  \
                                     (__attribute__((address_space(3))) void*)_d,        \
                                     16, 0, 0);                                          \
    __builtin_amdgcn_global_load_lds(                                                    \
        (const __attribute__((address_space(1))) void*)(_s + (size_t)64 * K),            \
        (__attribute__((address_space(3))) void*)(_d + 4096), 16, 0, 0);                 \
} while (0)

// read A fragments for row-half MH (8 x ds_read_b128, swizzled)
#define READ_A(BUF, MH) do {                                                             \
    const bf16_t* _As = &lds[(BUF) * 32768 + wm * 8192];                                 \
    _Pragma("unroll") for (int m = 0; m < 4; ++m)                                        \
        _Pragma("unroll") for (int kk = 0; kk < 2; ++kk)                                 \
            af[m][kk] = *(const bf16x8*)&_As[((MH) * 64 + m * 16 + fr) * 64 +            \
                                             ((((kk << 2) | hi) ^ fr7) << 3)];           \
} while (0)

// read B fragments for col-half NH (4 x ds_read_b128, swizzled)
#define READ_B(BUF, NH, BF) do {                                                         \
    const bf16_t* _Bs = &lds[(BUF) * 32768 + 16384 + (wn >> 1) * 8192];                  \
    _Pragma("unroll") for (int n = 0; n < 2; ++n)                                        \
        _Pragma("unroll") for (int kk = 0; kk < 2; ++kk)                                 \
            BF[n][kk] = *(const bf16x8*)&_Bs[((wn & 1) * 64 + ((NH) * 2 + n) * 16 + fr)  \
                                                 * 64 +                                  \
                                             ((((kk << 2) | hi) ^ fr7) << 3)];           \
} while (0)

// 16 MFMA = one C-quadrant x K=64 (no setprio: R17 isolated it as -5.6%)
#define QUAD(MH, NH, BF) do {                                                            \
    _Pragma("unroll") for (int m = 0; m < 4; ++m)                                        \
        _Pragma("unroll") for (int n = 0; n < 2; ++n)                                    \
            _Pragma("unroll") for (int kk = 0; kk < 2; ++kk)                             \
                acc[(MH) * 4 + m][(NH) * 2 + n] =                                        \
                    __builtin_amdgcn_mfma_f32_16x16x32_bf16(                             \
                        af[m][kk], BF[n][kk], acc[(MH) * 4 + m][(NH) * 2 + n], 0, 0, 0); \
} while (0)

// One K-tile = 4 phases; quadrant order (0,0),(0,1),(1,0),(1,1).
// Reads: ph0 af0+b0f (12), ph1 b1f (4), ph2 af1 (8), ph3 none.
// No manual lgkm waits: compiler emits per-use lgkmcnt so MFMA overlaps the
// tail of each LDS burst. Staging spread: ph0 buf^1.B1<-t+1, ph1 buf^1.A1<-t+1,
// ph2 buf.B0<-t+2, ph3 buf.A0<-t+2.
// Barriers: end-ph1 (WAR fence, REQUIRED -- R18 raced without it) and
// end-ph3 (boundary, after counted vmcnt(4)).
#define TILE(BUF, T, S01, S23, ENDW) do {                                                \
    /* phase 0 */                                                                        \
    READ_A(BUF, 0);                                                                      \
    READ_B(BUF, 0, b0f);                                                                 \
    if (S01) STAGE(((BUF) ^ 1) * 32768 + 3 * 8192, srcB1 + (size_t)((T) + 1) * 64);      \
    QUAD(0, 0, b0f);                                                                     \
    /* phase 1 */                                                                        \
    READ_B(BUF, 1, b1f);                                                                 \
    if (S01) STAGE(((BUF) ^ 1) * 32768 + 1 * 8192, srcA1 + (size_t)((T) + 1) * 64);      \
    QUAD(0, 1, b1f);                                                                     \
    BARF();   /* mid-tile WAR fence */                                                   \
    /* phase 2 */                                                                        \
    READ_A(BUF, 1);                                                                      \
    if (S23) STAGE((BUF) * 32768 + 2 * 8192, srcB0 + (size_t)((T) + 2) * 64);            \
    QUAD(1, 0, b0f);                                                                     \
    /* phase 3 (no reads; MFMA on resident regs) */                                      \
    if (S23) STAGE((BUF) * 32768 + 0 * 8192, srcA0 + (size_t)((T) + 2) * 64);            \
    QUAD(1, 1, b1f);                                                                     \
    if ((ENDW) == 4) VMW(4);                                                             \
    else if ((ENDW) == 0) VMW(0);                                                        \
    BARF();   /* tile boundary */                                                        \
} while (0)

__global__ __launch_bounds__(512, 2)
void gemm256_kernel(const bf16_t* __restrict__ A,
                    const bf16_t* __restrict__ B,
                    const float* __restrict__ bias,
                    float* __restrict__ C,
                    int M, int N, int K) {
    // 128 KiB: buf{0,1} x slots {A0,A1,B0,B1} x 8192 bf16 (128 rows x 64 cols)
    __shared__ bf16_t lds[65536];

    const int ntn = N / BN;
    const int nwg = gridDim.x;
    // bijective XCD swizzle (8 XCDs)
    const int q = nwg >> 3, r = nwg & 7;
    const int xcd = blockIdx.x & 7, lid = blockIdx.x >> 3;
    const int swz = (xcd < r ? xcd * (q + 1) : r * (q + 1) + (xcd - r) * q) + lid;
    const int tile_m = (swz / ntn) * BM;
    const int tile_n = (swz % ntn) * BN;

    const int tid = threadIdx.x;
    const int lane = tid & 63;
    const int wid = tid >> 6;
    const int wm = wid >> 2;   // 0..1: row half
    const int wn = wid & 3;    // 0..3: col quarter
    const int fr = lane & 15;
    const int hi = lane >> 4;
    const int fr7 = fr & 7;

    // inverse-swizzled global source column (bytes 4-6 ^= row bits 0-2; row=tid>>3)
    const int colsrc_e = ((((tid & 7) * 16) ^ ((tid & 56) << 1)) >> 1);
    const bf16_t* srcA0 = A + (size_t)(tile_m + (tid >> 3)) * K + colsrc_e;
    const bf16_t* srcA1 = srcA0 + (size_t)128 * K;
    const bf16_t* srcB0 = B + (size_t)(tile_n + (tid >> 3)) * K + colsrc_e;
    const bf16_t* srcB1 = srcB0 + (size_t)128 * K;

    bf16x8 af[4][2], b0f[2][2], b1f[2][2];
    f32x4 acc[8][4] = {};

    // prologue: tile0 fully + tile1's B0/A0; drain to 4 outstanding
    // (tile0 landed, tile1 B0/A0 in flight -> matches steady state).
    STAGE(16384, srcB0);               // buf0.B0 t0
    STAGE(0, srcA0);                   // buf0.A0 t0
    STAGE(24576, srcB1);               // buf0.B1 t0
    STAGE(8192, srcA1);                // buf0.A1 t0
    STAGE(32768 + 16384, srcB0 + 64);  // buf1.B0 t1
    STAGE(32768 + 0, srcA0 + 64);      // buf1.A0 t1
    VMW(4);
    BARF();

    const int npairs = K / 128;        // 2 K-tiles per iteration
    for (int i = 0; i < npairs - 1; ++i) {
        TILE(0, 2 * i, 1, 1, 4);
        TILE(1, 2 * i + 1, 1, 1, 4);
    }
    // tail: tile 2np-2 stages B1/A1(2np-1) only; drain all at its boundary
    TILE(0, 2 * npairs - 2, 1, 0, 0);
    TILE(1, 2 * npairs - 1, 0, 0, -1);

    // epilogue: C/D layout col=lane&15, row=(lane>>4)*4+reg
    float qb[4];
#pragma unroll
    for (int ng = 0; ng < 4; ++ng)
        qb[ng] = q16(bias[tile_n + wn * 64 + ng * 16 + fr]);
#pragma unroll
    for (int mg = 0; mg < 8; ++mg) {
        const int grow0 = tile_m + wm * 128 + mg * 16 + hi * 4;
#pragma unroll
        for (int ng = 0; ng < 4; ++ng) {
            const int gcol = tile_n + wn * 64 + ng * 16 + fr;
#pragma unroll
            for (int rr = 0; rr < 4; ++rr)
                C[(size_t)(grow0 + rr) * N + gcol] = acc[mg][ng][rr] + qb[ng];
        }
    }
}

extern "C" void kernel_launch(void* const* d_in, const int* in_sizes, int n_in,
                              void* d_out, int out_size, void* d_ws, size_t ws_size,
                              hipStream_t stream) {
    const float* inp   = (const float*)d_in[0];
    const float* shift = (const float*)d_in[1];
    const float* sign_ = (const float*)d_in[2];
    const float* bias  = (const float*)d_in[3];
    float* out = (float*)d_out;

    const int OUT_F = in_sizes[3];              // 4096
    const int IN_F  = in_sizes[1] / OUT_F;      // 4096
    const int Mrows = in_sizes[0] / IN_F;       // 4096

    bf16_t* Aq = (bf16_t*)d_ws;
    bf16_t* Wq = Aq + (size_t)Mrows * IN_F;     // (M*K + N*K)*2 = 67.2 MB of ws

    const int nA = Mrows * IN_F;                // == OUT_F * IN_F here

    convert_kernel<<<2048, 256, 0, stream>>>(inp, shift, sign_, Aq, Wq, nA >> 2);

    dim3 grid((Mrows / BM) * (OUT_F / BN));
    gemm256_kernel<<<grid, 512, 0, stream>>>(Aq, Wq, bias, out,
                                             Mrows, OUT_F, IN_F);
}